// Round 1
// 4452.552 us; speedup vs baseline: 4.6020x; 4.6020x over previous
//
#include <hip/hip_runtime.h>

typedef unsigned short u16;
typedef __attribute__((ext_vector_type(8))) short short8;   // 8 bf16 = 4 VGPRs (MFMA A/B frag)
typedef __attribute__((ext_vector_type(4))) float f32x4;    // MFMA C/D frag

#define N 1024
#define NSQ (1024 * 1024)
#define NITER 30

__device__ __forceinline__ float b2f(u16 u) {
  union { unsigned int i; float f; } v;
  v.i = ((unsigned int)u) << 16;
  return v.f;
}

__device__ __forceinline__ u16 f2b(float f) {
  union { float f; unsigned int i; } v;
  v.f = f;
  return (u16)((v.i + 0x7fffu + ((v.i >> 16) & 1u)) >> 16);
}

// ---- input dtype detection (unchanged) -------------------------------------
__global__ void k_flag(const u16* a, float* flag) {
  if (threadIdx.x == 0 && blockIdx.x == 0) {
    int cnt = 0;
    for (int i = 0; i < 256; ++i) {
      const u16 u = a[2 * i];
      const int e = (u >> 7) & 0xFF;
      if (e >= 100 && e <= 132) ++cnt;
    }
    *flag = (cnt >= 128) ? 1.0f : 0.0f;
  }
}

__global__ void k_sentinel(void* out, const float* flag) {
  if (threadIdx.x == 0 && blockIdx.x == 0) {
    if (*flag > 0.5f) ((u16*)out)[0] = f2b(1000.0f);
    else              ((float*)out)[0] = 1000.0f;
  }
}

__global__ void k_cvt2(const void* a, float* o, const float* flag, int n) {
  const int i = blockIdx.x * 256 + threadIdx.x;
  if (i < n) {
    if (*flag > 0.5f) o[i] = b2f(((const u16*)a)[i]);
    else              o[i] = ((const float*)a)[i];
  }
}

// ---- fp32 -> bf16 (hi, lo) split helpers -----------------------------------
__global__ void k_split(const float* x, u16* h, u16* l) {
  const int i = blockIdx.x * 256 + threadIdx.x;
  const float v = x[i];
  const u16 hi = f2b(v);
  h[i] = hi;
  l[i] = f2b(v - b2f(hi));
}

// T = A^T, split to bf16 hi/lo.  grid (32,32), block (32,8)
__global__ void k_tsplit(const float* A, u16* Th, u16* Tl) {
  __shared__ float s[32][33];
  const int bx = blockIdx.x, by = blockIdx.y;
  const int tx = threadIdx.x, ty = threadIdx.y;
  for (int p = 0; p < 4; ++p)
    s[ty + p * 8][tx] = A[(by * 32 + ty + p * 8) * N + bx * 32 + tx];
  __syncthreads();
  for (int p = 0; p < 4; ++p) {
    const int rT = bx * 32 + ty + p * 8;
    const int cT = by * 32 + tx;
    const float v = s[tx][ty + p * 8];   // = A[cT][rT]
    const u16 hi = f2b(v);
    Th[rT * N + cT] = hi;
    Tl[rT * N + cT] = f2b(v - b2f(hi));
  }
}

__global__ void k_fillsplit(u16* h, u16* l, float v) {
  const int i = blockIdx.x * 256 + threadIdx.x;
  const u16 hi = f2b(v);
  h[i] = hi;
  l[i] = f2b(v - b2f(hi));
}

// ---- split-fp32 NT GEMM via bf16 MFMA --------------------------------------
// C[m][n] (=) sum_p sum_k P_p[m][k] * Q_p[n][k]   (i.e. C = sum_p P_p * Q_p^T)
// P, Q given pre-split as bf16 (hi, lo); product uses hi*hi + hi*lo + lo*hi
// with fp32 MFMA accumulation (~2^-17 relative error, fp32-class).
// Optionally writes C fp32 and/or C's own bf16 hi/lo split for downstream GEMMs.
struct NTJob {
  const u16* ph[2]; const u16* pl[2];
  const u16* qh[2]; const u16* ql[2];
  float* c; u16* ch; u16* cl;
  int npairs; int wantc; int wantsplit;
};
struct NTBatch { NTJob j[4]; };

#define GLDS(g, l) __builtin_amdgcn_global_load_lds(                         \
    (const __attribute__((address_space(1))) void*)(g),                      \
    (__attribute__((address_space(3))) void*)(l), 16, 0, 0)

// BM = 128 fixed, BK = 32; 4 waves as 2x2, per-wave tile 64 x (BN/2).
// LDS tiles [row][k] with 16B-chunk XOR swizzle (slot ^= (row>>1)&3) so both
// staging (global_load_lds, linear dest + pre-swizzled per-lane source) and
// ds_read_b128 fragment reads are bank-conflict-free.
template <int BN>
__global__ __launch_bounds__(256) void k_nt(NTBatch batch) {
  constexpr int NT_ = BN / 32;            // 16-wide n-tiles per wave
  __shared__ u16 Ah[128][32];
  __shared__ u16 Al[128][32];
  __shared__ u16 Bh[BN][32];
  __shared__ u16 Bl[BN][32];

  const NTJob job = batch.j[blockIdx.z];
  const int tid = threadIdx.x;
  const int w = tid >> 6, lane = tid & 63;
  const int m0 = blockIdx.y * 128, n0 = blockIdx.x * BN;

  // --- staging per-lane constants (byte offsets into the u16 matrices) ---
  const int srow = lane >> 2;             // 0..15: row within a 16-row wave-load
  const int sch  = lane & 3;              // dest 16B slot
  const int arow = w * 32 + srow;         // A rows: 32 per wave
  const long aoff = (long)(m0 + arow) * (N * 2) + (long)((sch ^ ((arow >> 1) & 3)) << 4);
  const int brow = w * (BN / 4) + srow;   // B rows: BN/4 per wave
  const long boff = (long)(n0 + brow) * (N * 2) + (long)((sch ^ ((brow >> 1) & 3)) << 4);

  // --- fragment read indices (constant across K steps) ---
  const int r0 = lane & 15, g = lane >> 4;
  const int wr = w & 1, wc = w >> 1;
  const int wm = wr * 64, wn = wc * (BN / 2);
  int idxA[4], idxB[NT_];
#pragma unroll
  for (int mt = 0; mt < 4; ++mt) {
    const int row = wm + mt * 16 + r0;
    idxA[mt] = row * 32 + ((g ^ ((row >> 1) & 3)) << 3);
  }
#pragma unroll
  for (int nt = 0; nt < NT_; ++nt) {
    const int row = wn + nt * 16 + r0;
    idxB[nt] = row * 32 + ((g ^ ((row >> 1) & 3)) << 3);
  }

  f32x4 acc[4][NT_];
#pragma unroll
  for (int mt = 0; mt < 4; ++mt)
#pragma unroll
    for (int nt = 0; nt < NT_; ++nt)
      acc[mt][nt] = (f32x4){0.0f, 0.0f, 0.0f, 0.0f};

  auto issue = [&](int s) {
    const int pair = s >> 5;
    const long kb = (long)(s & 31) * 64;
    const char* pA_h = (const char*)job.ph[pair] + aoff + kb;
    const char* pA_l = (const char*)job.pl[pair] + aoff + kb;
    const char* pB_h = (const char*)job.qh[pair] + boff + kb;
    const char* pB_l = (const char*)job.ql[pair] + boff + kb;
    GLDS(pA_h,         &Ah[w * 32][0]);
    GLDS(pA_h + 32768, &Ah[w * 32 + 16][0]);
    GLDS(pA_l,         &Al[w * 32][0]);
    GLDS(pA_l + 32768, &Al[w * 32 + 16][0]);
    GLDS(pB_h,         &Bh[w * (BN / 4)][0]);
    GLDS(pB_l,         &Bl[w * (BN / 4)][0]);
    if constexpr (BN == 128) {
      GLDS(pB_h + 32768, &Bh[w * 32 + 16][0]);
      GLDS(pB_l + 32768, &Bl[w * 32 + 16][0]);
    }
  };

  const int nsteps = job.npairs * 32;
  issue(0);
  const u16* Ahf = &Ah[0][0];
  const u16* Alf = &Al[0][0];
  const u16* Bhf = &Bh[0][0];
  const u16* Blf = &Bl[0][0];

  for (int s = 0; s < nsteps; ++s) {
    __syncthreads();                       // drains vmcnt (global_load_lds) + barrier
    short8 ah[4], al[4];
#pragma unroll
    for (int mt = 0; mt < 4; ++mt) {
      ah[mt] = *(const short8*)(Ahf + idxA[mt]);
      al[mt] = *(const short8*)(Alf + idxA[mt]);
    }
#pragma unroll
    for (int nt = 0; nt < NT_; ++nt) {
      const short8 bh = *(const short8*)(Bhf + idxB[nt]);
      const short8 bl = *(const short8*)(Blf + idxB[nt]);
#pragma unroll
      for (int mt = 0; mt < 4; ++mt) {
        acc[mt][nt] = __builtin_amdgcn_mfma_f32_16x16x32_bf16(ah[mt], bh, acc[mt][nt], 0, 0, 0);
        acc[mt][nt] = __builtin_amdgcn_mfma_f32_16x16x32_bf16(ah[mt], bl, acc[mt][nt], 0, 0, 0);
        acc[mt][nt] = __builtin_amdgcn_mfma_f32_16x16x32_bf16(al[mt], bh, acc[mt][nt], 0, 0, 0);
      }
    }
    __syncthreads();                       // all waves done reading LDS
    if (s + 1 < nsteps) issue(s + 1);
  }

  // C/D layout (m89-verified): col = lane&15, row = (lane>>4)*4 + reg
#pragma unroll
  for (int mt = 0; mt < 4; ++mt) {
    const int crow = m0 + wm + mt * 16 + g * 4;
#pragma unroll
    for (int nt = 0; nt < NT_; ++nt) {
      const int ccol = n0 + wn + nt * 16 + r0;
#pragma unroll
      for (int jj = 0; jj < 4; ++jj) {
        const float v = acc[mt][nt][jj];
        const int o = (crow + jj) * N + ccol;
        if (job.wantc) job.c[o] = v;
        if (job.wantsplit) {
          const u16 hi = f2b(v);
          job.ch[o] = hi;
          job.cl[o] = f2b(v - b2f(hi));
        }
      }
    }
  }
}

// ---- reductions (unchanged) -------------------------------------------------
__global__ void k_rsum(const float* x, float* slot) {
  __shared__ float red[256];
  const int tid = threadIdx.x;
  float a = 0.0f;
  for (int i = blockIdx.x * 256 + tid; i < NSQ; i += gridDim.x * 256)
    a += x[i] * x[i];
  red[tid] = a;
  __syncthreads();
  for (int off = 128; off > 0; off >>= 1) {
    if (tid < off) red[tid] += red[tid + off];
    __syncthreads();
  }
  if (tid == 0) atomicAdd(slot, red[0]);
}

__global__ void k_dot(const float* x, const float* y, float* slot) {
  __shared__ float red[256];
  const int tid = threadIdx.x;
  float a = 0.0f;
  for (int i = blockIdx.x * 256 + tid; i < NSQ; i += gridDim.x * 256)
    a += x[i] * y[i];
  red[tid] = a;
  __syncthreads();
  for (int off = 128; off > 0; off >>= 1) {
    if (tid < off) red[tid] += red[tid + off];
    __syncthreads();
  }
  if (tid == 0) atomicAdd(slot, red[0]);
}

__global__ void k_zero(float* p) {
  const int i = blockIdx.x * 256 + threadIdx.x;
  p[i] = 0.0f;
}

// Finalize. Unnormalized iterates: eig = <r,Tr>/<r,r>, E0 = sum h*dots/(lr*eig^2).
__global__ void GMPOmodel_6794638262737_kernel(const void* h, const float* slots,
                                               void* out) {
  if (threadIdx.x == 0 && blockIdx.x == 0) {
    const float bf = slots[512];
    const float rr = slots[399];
    const float rw = slots[400];
    const float lr = slots[401];
    const float eig = rw / rr;
    float num = 0.0f;
    for (int u = 0; u < 16; ++u) {
      const float hv = (bf > 0.5f) ? b2f(((const u16*)h)[u]) : ((const float*)h)[u];
      num += hv * slots[402 + u];
    }
    const float e0 = num / (lr * eig * eig);
    if (bf > 0.5f) ((u16*)out)[0] = f2b(e0);
    else           ((float*)out)[0] = e0;
  }
}

// ---- host -------------------------------------------------------------------
static inline NTJob mkjob(const u16* ph0, const u16* pl0, const u16* qh0, const u16* ql0,
                          const u16* ph1, const u16* pl1, const u16* qh1, const u16* ql1,
                          float* c, u16* ch, u16* cl, int npairs, int wantc, int wantsplit) {
  NTJob j;
  j.ph[0] = ph0; j.pl[0] = pl0; j.qh[0] = qh0; j.ql[0] = ql0;
  j.ph[1] = ph1; j.pl[1] = pl1; j.qh[1] = qh1; j.ql[1] = ql1;
  j.c = c; j.ch = ch; j.cl = cl;
  j.npairs = npairs; j.wantc = wantc; j.wantsplit = wantsplit;
  return j;
}

extern "C" void kernel_launch(void* const* d_in, const int* in_sizes, int n_in,
                              void* d_out, int out_size, void* d_ws, size_t ws_size,
                              hipStream_t stream) {
  (void)in_sizes; (void)n_in; (void)out_size; (void)ws_size;
  const void* Ain = d_in[0];
  const void* hin = d_in[1];
  char* ws = (char*)d_ws;
  const size_t MB = 1u << 20;

  // bf16 split buffers (2 MB each)
  u16* A0h = (u16*)(ws + 0 * MB);   u16* A0l = (u16*)(ws + 2 * MB);
  u16* A1h = (u16*)(ws + 4 * MB);   u16* A1l = (u16*)(ws + 6 * MB);
  u16* T0h = (u16*)(ws + 8 * MB);   u16* T0l = (u16*)(ws + 10 * MB);
  u16* T1h = (u16*)(ws + 12 * MB);  u16* T1l = (u16*)(ws + 14 * MB);
  u16* rh  = (u16*)(ws + 16 * MB);  u16* rl  = (u16*)(ws + 18 * MB);
  u16* lh  = (u16*)(ws + 20 * MB);  u16* ll  = (u16*)(ws + 22 * MB);
  u16* t0rh = (u16*)(ws + 24 * MB); u16* t0rl = (u16*)(ws + 26 * MB);
  u16* t1rh = (u16*)(ws + 28 * MB); u16* t1rl = (u16*)(ws + 30 * MB);
  u16* t0lh = (u16*)(ws + 32 * MB); u16* t0ll = (u16*)(ws + 34 * MB);
  u16* t1lh = (u16*)(ws + 36 * MB); u16* t1ll = (u16*)(ws + 38 * MB);
  // fp32 buffers (4 MB each); A0f/A1f are reused as L00/L01, wf as U00
  float* A0f = (float*)(ws + 40 * MB);   // setup A0 fp32 -> epilogue L00
  float* A1f = (float*)(ws + 44 * MB);   // setup A1 fp32 -> epilogue L01
  float* rf  = (float*)(ws + 48 * MB);
  float* lf  = (float*)(ws + 52 * MB);
  float* wf  = (float*)(ws + 56 * MB);   // mv_r(r) -> epilogue U00
  float* L10 = (float*)(ws + 60 * MB);
  float* L11 = (float*)(ws + 64 * MB);
  float* U01 = (float*)(ws + 68 * MB);
  float* U10 = (float*)(ws + 72 * MB);
  float* U11 = (float*)(ws + 76 * MB);
  float* slots = (float*)(ws + 80 * MB); // 1024 floats; [512] = dtype flag

  k_zero<<<4, 256, 0, stream>>>(slots);
  k_flag<<<1, 64, 0, stream>>>((const u16*)Ain, slots + 512);
  k_sentinel<<<1, 64, 0, stream>>>(d_out, slots + 512);
  k_cvt2<<<8192, 256, 0, stream>>>(Ain, A0f, slots + 512, 2 * NSQ);  // fills A0f, A1f

  k_split<<<4096, 256, 0, stream>>>(A0f, A0h, A0l);
  k_split<<<4096, 256, 0, stream>>>(A1f, A1h, A1l);
  k_tsplit<<<dim3(32, 32), dim3(32, 8), 0, stream>>>(A0f, T0h, T0l);
  k_tsplit<<<dim3(32, 32), dim3(32, 8), 0, stream>>>(A1f, T1h, T1l);
  k_fillsplit<<<4096, 256, 0, stream>>>(rh, rl, 1.0f / 1024.0f);
  k_fillsplit<<<4096, 256, 0, stream>>>(lh, ll, 1.0f / 1024.0f);

  // r, l are symmetric throughout (v0 symmetric, map preserves symmetry), so
  // every GEMM is NT form: C = P * Q^T with Q stored row-major as shown.
  // Stage 1 (z=4): t0r=A0*r, t1r=A1*r, t0l=A0^T*l, t1l=A1^T*l (split-only out)
  NTBatch s1;
  s1.j[0] = mkjob(A0h, A0l, rh, rl, 0, 0, 0, 0, 0, t0rh, t0rl, 1, 0, 1);
  s1.j[1] = mkjob(A1h, A1l, rh, rl, 0, 0, 0, 0, 0, t1rh, t1rl, 1, 0, 1);
  s1.j[2] = mkjob(T0h, T0l, lh, ll, 0, 0, 0, 0, 0, t0lh, t0ll, 1, 0, 1);
  s1.j[3] = mkjob(T1h, T1l, lh, ll, 0, 0, 0, 0, 0, t1lh, t1ll, 1, 0, 1);
  // Stage 2 (z=2, dual-pair): r' = t0r*A0^T + t1r*A1^T ; l' = t0l*A0 + t1l*A1
  // (in-place split overwrite of r/l is safe: stage 2 never reads them)
  NTBatch s2;
  s2.j[0] = mkjob(t0rh, t0rl, A0h, A0l, t1rh, t1rl, A1h, A1l, rf, rh, rl, 2, 1, 1);
  s2.j[1] = mkjob(t0lh, t0ll, T0h, T0l, t1lh, t1ll, T1h, T1l, lf, lh, ll, 2, 1, 1);

  for (int it = 0; it < NITER; ++it) {
    k_nt<128><<<dim3(8, 8, 4), 256, 0, stream>>>(s1);
    k_nt<64><<<dim3(16, 8, 2), 256, 0, stream>>>(s2);
  }

  // ---- epilogue (unnormalized; E0 homogeneous deg 0 in r and l) ----
  // w = mv_r(r_final): recompute t with final r, then dual-pair reduce
  NTBatch e1;
  e1.j[0] = mkjob(A0h, A0l, rh, rl, 0, 0, 0, 0, 0, t0rh, t0rl, 1, 0, 1);
  e1.j[1] = mkjob(A1h, A1l, rh, rl, 0, 0, 0, 0, 0, t1rh, t1rl, 1, 0, 1);
  k_nt<128><<<dim3(8, 8, 2), 256, 0, stream>>>(e1);
  NTBatch e2;
  e2.j[0] = mkjob(t0rh, t0rl, A0h, A0l, t1rh, t1rl, A1h, A1l, wf, 0, 0, 2, 1, 0);
  k_nt<64><<<dim3(16, 8, 1), 256, 0, stream>>>(e2);
  k_rsum<<<256, 256, 0, stream>>>(rf, slots + 399);          // rr
  k_dot<<<256, 256, 0, stream>>>(rf, wf, slots + 400);       // rw
  k_dot<<<256, 256, 0, stream>>>(lf, rf, slots + 401);       // lr

  // UL_a = l*A_a = NT(l, ATa); URT_b = (A_b r)^T = r*A_b^T = NT(r, A_b)
  // (t-buffers are dead after e2 -> reuse as UL/URT split storage)
  NTBatch e3;
  e3.j[0] = mkjob(lh, ll, T0h, T0l, 0, 0, 0, 0, 0, t0lh, t0ll, 1, 0, 1);  // UL0
  e3.j[1] = mkjob(lh, ll, T1h, T1l, 0, 0, 0, 0, 0, t1lh, t1ll, 1, 0, 1);  // UL1
  e3.j[2] = mkjob(rh, rl, A0h, A0l, 0, 0, 0, 0, 0, t0rh, t0rl, 1, 0, 1);  // URT0
  e3.j[3] = mkjob(rh, rl, A1h, A1l, 0, 0, 0, 0, 0, t1rh, t1rl, 1, 0, 1);  // URT1
  k_nt<128><<<dim3(8, 8, 4), 256, 0, stream>>>(e3);

  // L_cd = A_c*A_d = NT(A_c, ATd); fp32 only. A0f/A1f fp32 are dead -> L00/L01.
  NTBatch e4;
  e4.j[0] = mkjob(A0h, A0l, T0h, T0l, 0, 0, 0, 0, A0f, 0, 0, 1, 1, 0);
  e4.j[1] = mkjob(A0h, A0l, T1h, T1l, 0, 0, 0, 0, A1f, 0, 0, 1, 1, 0);
  e4.j[2] = mkjob(A1h, A1l, T0h, T0l, 0, 0, 0, 0, L10, 0, 0, 1, 1, 0);
  e4.j[3] = mkjob(A1h, A1l, T1h, T1l, 0, 0, 0, 0, L11, 0, 0, 1, 1, 0);
  k_nt<128><<<dim3(8, 8, 4), 256, 0, stream>>>(e4);

  // U_ab = UL_a * UR_b = NT(UL_a, URT_b); wf dead after rw dot -> U00.
  NTBatch e5;
  e5.j[0] = mkjob(t0lh, t0ll, t0rh, t0rl, 0, 0, 0, 0, wf,  0, 0, 1, 1, 0);
  e5.j[1] = mkjob(t0lh, t0ll, t1rh, t1rl, 0, 0, 0, 0, U01, 0, 0, 1, 1, 0);
  e5.j[2] = mkjob(t1lh, t1ll, t0rh, t0rl, 0, 0, 0, 0, U10, 0, 0, 1, 1, 0);
  e5.j[3] = mkjob(t1lh, t1ll, t1rh, t1rl, 0, 0, 0, 0, U11, 0, 0, 1, 1, 0);
  k_nt<128><<<dim3(8, 8, 4), 256, 0, stream>>>(e5);

  float* Us[4] = {wf, U01, U10, U11};
  float* Ls[4] = {A0f, A1f, L10, L11};
  for (int ab = 0; ab < 4; ++ab)
    for (int cd = 0; cd < 4; ++cd)
      k_dot<<<256, 256, 0, stream>>>(Us[ab], Ls[cd], slots + 402 + ab * 4 + cd);

  GMPOmodel_6794638262737_kernel<<<1, 64, 0, stream>>>(hin, slots, d_out);
}